// Round 11
// baseline (447.708 us; speedup 1.0000x reference)
//
#include <hip/hip_runtime.h>
#include <hip/hip_bf16.h>
#include <math.h>

#define NN 512

typedef __attribute__((ext_vector_type(8))) short short8;
typedef __attribute__((ext_vector_type(4))) float f32x4;

__device__ __forceinline__ float selu_f(float x) {
    const float sc = 1.0507009873554805f, al = 1.6732632423543772f;
    return x > 0.f ? sc * x : sc * al * expm1f(x);
}
__device__ __forceinline__ unsigned short f2b(float f) {
    unsigned int u = __float_as_uint(f);
    unsigned int r = (u + 0x7fffu + ((u >> 16) & 1u)) >> 16;
    return (unsigned short)r;
}
__device__ __forceinline__ float b2f(unsigned short h) {
    return __uint_as_float(((unsigned int)h) << 16);
}
__device__ __forceinline__ float ulo(unsigned int u) {
    return __uint_as_float(u << 16);
}
__device__ __forceinline__ float uhi(unsigned int u) {
    return __uint_as_float(u & 0xffff0000u);
}
__device__ __forceinline__ unsigned int pk2(float a, float b) {
    return (unsigned int)f2b(a) | ((unsigned int)f2b(b) << 16);
}
__device__ __forceinline__ void gload16(const void* g, void* l) {
    __builtin_amdgcn_global_load_lds(
        (const __attribute__((address_space(1))) unsigned int*)g,
        (__attribute__((address_space(3))) unsigned int*)l, 16, 0, 0);
}

// ---------------- graph construction (f32) ----------------

__global__ __launch_bounds__(64) void nodevec_kernel(
    const float* __restrict__ emb, const float* __restrict__ lw,
    const float* __restrict__ lb, float* __restrict__ nv) {
    int i = blockIdx.x, j = threadIdx.x;
    __shared__ float e_s[64];
    e_s[j] = emb[i * 64 + j];
    __syncthreads();
    float acc = lb[j];
    for (int k = 0; k < 64; k++) acc += e_s[k] * lw[j * 64 + k];
    nv[i * 64 + j] = tanhf(3.0f * acc);
}

__global__ __launch_bounds__(512) void adjacency_kernel(
    const float* __restrict__ nv1, const float* __restrict__ nv2,
    float* __restrict__ adj) {
    int v = blockIdx.x, w = threadIdx.x;
    __shared__ float a1s[64], a2s[64];
    if (threadIdx.x < 64) {
        a1s[threadIdx.x] = nv1[v * 64 + threadIdx.x];
        a2s[threadIdx.x] = nv2[v * 64 + threadIdx.x];
    }
    __syncthreads();
    float acc = 0.f;
    for (int k = 0; k < 64; k++) {
        acc += a1s[k] * nv2[w * 64 + k];
        acc -= a2s[k] * nv1[w * 64 + k];
    }
    adj[v * NN + w] = selu_f(tanhf(3.0f * acc));
}

__global__ __launch_bounds__(256) void topk_kernel(
    float* __restrict__ adj, float* __restrict__ rowsump) {
    __shared__ float orig[512], srt[512];
    __shared__ unsigned char keep[512];
    __shared__ float red[256];
    int v = blockIdx.x, t = threadIdx.x;
    orig[t] = adj[v * NN + t];
    orig[t + 256] = adj[v * NN + t + 256];
    srt[t] = orig[t];
    srt[t + 256] = orig[t + 256];
    __syncthreads();
    for (int k = 2; k <= 512; k <<= 1) {
        for (int j = k >> 1; j > 0; j >>= 1) {
            for (int pass = 0; pass < 2; ++pass) {
                int i = t + pass * 256;
                int ixj = i ^ j;
                if (ixj > i) {
                    bool up = ((i & k) == 0);
                    float a = srt[i], b = srt[ixj];
                    if ((a > b) == up) { srt[i] = b; srt[ixj] = a; }
                }
            }
            __syncthreads();
        }
    }
    float thr = srt[256];
    if (t == 0) {
        int g = 0;
        for (int i = 0; i < 512; i++) if (srt[i] > thr) g++;
        int quota = 256 - g;
        for (int w = 0; w < 512; w++) {
            float x = orig[w];
            bool kp = false;
            if (x > thr) kp = true;
            else if (x == thr && quota > 0) { kp = true; quota--; }
            keep[w] = kp ? 1 : 0;
        }
    }
    __syncthreads();
    float part = 0.f;
    for (int pass = 0; pass < 2; pass++) {
        int w = t + pass * 256;
        float val = keep[w] ? orig[w] : 0.0f;
        adj[v * NN + w] = val;
        part += val;
    }
    red[t] = part;
    __syncthreads();
    if (t < 128) red[t] += red[t + 128];
    __syncthreads();
    if (t < 64) {
        float x = red[t] + red[t + 64];
        for (int m = 32; m; m >>= 1) x += __shfl_xor(x, m, 64);
        if (t == 0) rowsump[v] = x + 1.0f;
    }
}

// column-sum phase 1: 16 blocks x 32 rows each, coalesced
__global__ __launch_bounds__(256) void colsum_part(
    const float* __restrict__ adp, float* __restrict__ part) {
    int b = blockIdx.x, w = threadIdx.x;
    float s0 = 0.f, s1 = 0.f;
    for (int r = 0; r < 32; r++) {
        s0 += adp[(b * 32 + r) * 512 + w];
        s1 += adp[(b * 32 + r) * 512 + w + 256];
    }
    part[b * 512 + w] = s0;
    part[b * 512 + w + 256] = s1;
}
__global__ __launch_bounds__(512) void colsum_red(
    const float* __restrict__ part, float* __restrict__ colsum) {
    int w = threadIdx.x;
    float s = 0.f;
    for (int b = 0; b < 16; b++) s += part[b * 512 + w];
    colsum[w] = s;
}

// adjacency stored hi/lo split: aT[w][0..511]=hi, aT[w][512..1023]=lo
__global__ __launch_bounds__(256) void normalize_kernel(
    const float* __restrict__ adp, const float* __restrict__ rowsump,
    const float* __restrict__ colsum, unsigned short* __restrict__ a1T,
    unsigned short* __restrict__ a2T) {
    int w = blockIdx.x;
    for (int v = threadIdx.x; v < NN; v += 256) {
        float d = (v == w) ? 1.0f : 0.0f;
        float f1 = (adp[v * NN + w] + d) / rowsump[v];
        float f2 = (adp[w * NN + v] + d) / (colsum[v] + 1.0f);
        unsigned short h1 = f2b(f1), h2 = f2b(f2);
        a1T[w * 1024 + v] = h1;
        a1T[w * 1024 + 512 + v] = f2b(f1 - b2f(h1));
        a2T[w * 1024 + v] = h2;
        a2T[w * 1024 + 512 + v] = f2b(f2 - b2f(h2));
    }
}

// ---------------- main pipeline ----------------
// h storage: [j=(n,c,l)][1024] bf16; cols 0..511 = hi, 512..1023 = lo.

__global__ __launch_bounds__(256) void start_kernel(
    const float* __restrict__ x, const float* __restrict__ sw,
    const float* __restrict__ sb, unsigned int* __restrict__ h_u) {
    int n = blockIdx.x >> 6, l = blockIdx.x & 63;
    int t = threadIdx.x;
    float x0 = x[(n * 512 + 2 * t) * 64 + l];
    float x1 = x[(n * 512 + 2 * t + 1) * 64 + l];
#pragma unroll
    for (int c = 0; c < 32; c++) {
        float wc = sw[c], bc = sb[c];
        float f0 = x0 * wc + bc;
        float f1 = x1 * wc + bc;
        unsigned short h0 = f2b(f0), h1 = f2b(f1);
        float l0 = f0 - b2f(h0), l1 = f1 - b2f(h1);
        int j = (n * 32 + c) * 64 + l;
        h_u[j * 512 + t] = (unsigned int)h0 | ((unsigned int)h1 << 16);
        h_u[j * 512 + 256 + t] = pk2(l0, l1);
    }
}

// Paired propagation; XCD-chunked block remap (T1). Unchanged (passing).
template <bool SHAREA>
__global__ __launch_bounds__(256, 2) void prop_pair(
    const unsigned short* __restrict__ HA, const unsigned short* __restrict__ HB,
    const unsigned short* __restrict__ base,
    const unsigned short* __restrict__ AT1,
    const unsigned short* __restrict__ AT2,
    unsigned short* __restrict__ dst1, unsigned short* __restrict__ dst2) {
    __shared__ __align__(16) short At1[128 * 64];
    __shared__ __align__(16) short At2[SHAREA ? 8 : 128 * 64];
    __shared__ __align__(16) short Bt1[64 * 64];
    __shared__ __align__(16) short Bt2[64 * 64];
    int t = threadIdx.x;
    int lane = t & 63;
    int wid = t >> 6;
    int wm = wid >> 1, wn = wid & 1;
    int flat = blockIdx.y * 64 + blockIdx.x;     // 0..511
    int wid_ = (flat & 7) * 64 + (flat >> 3);    // chunk of 64 per XCD
    int local = wid_ & 63;
    int j0 = (((wid_ >> 6) << 3) + (local & 7)) << 7;
    int w0 = (local >> 3) << 6;
    f32x4 acc1[4][2], acc2[4][2];
#pragma unroll
    for (int m = 0; m < 4; m++)
#pragma unroll
        for (int n = 0; n < 2; n++) {
            acc1[m][n] = (f32x4)0.f;
            acc2[m][n] = (f32x4)0.f;
        }
    int l15 = lane & 15;
    int lhi = lane >> 4;
    int rsw = l15 & 7;
    for (int tk = 0; tk < 24; tk++) {
        int kk = tk << 6;
        int ca = (kk < 1024) ? kk : (kk - 1024);
        int cb = (kk < 512) ? kk : (kk - 512);
#pragma unroll
        for (int it = 0; it < 4; it++) {
            int slot = it * 256 + t;
            int r = slot >> 3, sl = slot & 7;
            int src = (sl ^ (r & 7)) << 3;
            gload16(HA + (j0 + r) * 1024 + ca + src, &At1[slot * 8]);
            if constexpr (!SHAREA)
                gload16(HB + (j0 + r) * 1024 + ca + src, &At2[slot * 8]);
        }
#pragma unroll
        for (int it = 0; it < 2; it++) {
            int slot = it * 256 + t;
            int r = slot >> 3, sl = slot & 7;
            int src = (sl ^ (r & 7)) << 3;
            gload16(AT1 + (w0 + r) * 1024 + cb + src, &Bt1[slot * 8]);
            gload16(AT2 + (w0 + r) * 1024 + cb + src, &Bt2[slot * 8]);
        }
        __syncthreads();
#pragma unroll
        for (int kh = 0; kh < 2; kh++) {
            int soff = ((kh * 4 + lhi) ^ rsw) << 3;
            short8 a1[4], b1[2], b2[2];
#pragma unroll
            for (int m = 0; m < 4; m++)
                a1[m] =
                    *(const short8*)&At1[(wm * 64 + m * 16 + l15) * 64 + soff];
#pragma unroll
            for (int n = 0; n < 2; n++) {
                b1[n] =
                    *(const short8*)&Bt1[(wn * 32 + n * 16 + l15) * 64 + soff];
                b2[n] =
                    *(const short8*)&Bt2[(wn * 32 + n * 16 + l15) * 64 + soff];
            }
            if constexpr (SHAREA) {
#pragma unroll
                for (int m = 0; m < 4; m++)
#pragma unroll
                    for (int n = 0; n < 2; n++) {
                        acc1[m][n] = __builtin_amdgcn_mfma_f32_16x16x32_bf16(
                            a1[m], b1[n], acc1[m][n], 0, 0, 0);
                        acc2[m][n] = __builtin_amdgcn_mfma_f32_16x16x32_bf16(
                            a1[m], b2[n], acc2[m][n], 0, 0, 0);
                    }
            } else {
                short8 a2[4];
#pragma unroll
                for (int m = 0; m < 4; m++)
                    a2[m] = *(const short8*)&At2[(wm * 64 + m * 16 + l15) * 64 +
                                                 soff];
#pragma unroll
                for (int m = 0; m < 4; m++)
#pragma unroll
                    for (int n = 0; n < 2; n++) {
                        acc1[m][n] = __builtin_amdgcn_mfma_f32_16x16x32_bf16(
                            a1[m], b1[n], acc1[m][n], 0, 0, 0);
                        acc2[m][n] = __builtin_amdgcn_mfma_f32_16x16x32_bf16(
                            a2[m], b2[n], acc2[m][n], 0, 0, 0);
                    }
            }
        }
        __syncthreads();
    }
#pragma unroll
    for (int m = 0; m < 4; m++) {
#pragma unroll
        for (int n = 0; n < 2; n++) {
#pragma unroll
            for (int r = 0; r < 4; r++) {
                int row = j0 + wm * 64 + m * 16 + lhi * 4 + r;
                int col = w0 + wn * 32 + n * 16 + l15;
                int ih = row * 1024 + col;
                float bf = b2f(base[ih]) + b2f(base[ih + 512]);
                float f1 = 0.05f * bf + 0.95f * acc1[m][n][r];
                float f2 = 0.05f * bf + 0.95f * acc2[m][n][r];
                unsigned short h1 = f2b(f1);
                unsigned short h2 = f2b(f2);
                dst1[ih] = h1;
                dst1[ih + 512] = f2b(f1 - b2f(h1));
                dst2[ih] = h2;
                dst2[ih + 512] = f2b(f2 - b2f(h2));
            }
        }
    }
}

// dual chanmix (unchanged, passing).
__global__ __launch_bounds__(256) void chanmix_dual(
    const unsigned int* __restrict__ h0, const unsigned int* __restrict__ p1a,
    const unsigned int* __restrict__ p2a, const unsigned int* __restrict__ p1b,
    const unsigned int* __restrict__ p2b, const float* __restrict__ w1,
    const float* __restrict__ b1, const float* __restrict__ w2,
    const float* __restrict__ b2, unsigned int* __restrict__ dst_u) {
    __shared__ float w1s[3072], w2s[3072];
    int bid = blockIdx.x;
    int vc = bid & 3, l = (bid >> 2) & 63, n = bid >> 8;
    int t = threadIdx.x;
    int vl = t & 63, q = t >> 6;
    for (int i = t; i < 3072; i += 256) {
        w1s[i] = w1[i];
        w2s[i] = w2[i];
    }
    __syncthreads();
    float acc[8][2];
#pragma unroll
    for (int oo = 0; oo < 8; oo++) {
        float bb = b1[q * 8 + oo] + b2[q * 8 + oo];
        acc[oo][0] = bb;
        acc[oo][1] = bb;
    }
    int uoff = vc * 64 + vl;
    for (int c = 0; c < 32; c++) {
        int j = (n * 32 + c) * 64 + l;
        unsigned int u0h = h0[j * 512 + uoff], u0l = h0[j * 512 + 256 + uoff];
        unsigned int uah = p1a[j * 512 + uoff], ual = p1a[j * 512 + 256 + uoff];
        unsigned int ubh = p2a[j * 512 + uoff], ubl = p2a[j * 512 + 256 + uoff];
        unsigned int uch = p1b[j * 512 + uoff], ucl = p1b[j * 512 + 256 + uoff];
        unsigned int udh = p2b[j * 512 + uoff], udl = p2b[j * 512 + 256 + uoff];
        float x0l = ulo(u0h) + ulo(u0l), x0h = uhi(u0h) + uhi(u0l);
        float xal = ulo(uah) + ulo(ual), xah = uhi(uah) + uhi(ual);
        float xbl = ulo(ubh) + ulo(ubl), xbh = uhi(ubh) + uhi(ubl);
        float xcl = ulo(uch) + ulo(ucl), xch = uhi(uch) + uhi(ucl);
        float xdl = ulo(udh) + ulo(udl), xdh = uhi(udh) + uhi(udl);
#pragma unroll
        for (int oo = 0; oo < 8; oo++) {
            int o = q * 8 + oo;
            float wa0 = w1s[o * 96 + c];
            float wa1 = w1s[o * 96 + 32 + c];
            float wa2 = w1s[o * 96 + 64 + c];
            float wb0 = w2s[o * 96 + c];
            float wb1 = w2s[o * 96 + 32 + c];
            float wb2 = w2s[o * 96 + 64 + c];
            acc[oo][0] += x0l * wa0 + xal * wa1 + xbl * wa2 + x0l * wb0 +
                          xcl * wb1 + xdl * wb2;
            acc[oo][1] += x0h * wa0 + xah * wa1 + xbh * wa2 + x0h * wb0 +
                          xch * wb1 + xdh * wb2;
        }
    }
#pragma unroll
    for (int oo = 0; oo < 8; oo++) {
        int o = q * 8 + oo;
        int j = (n * 32 + o) * 64 + l;
        float a0 = acc[oo][0], a1 = acc[oo][1];
        unsigned short hi0 = f2b(a0), hi1 = f2b(a1);
        dst_u[j * 512 + uoff] = (unsigned int)hi0 | ((unsigned int)hi1 << 16);
        dst_u[j * 512 + 256 + uoff] = pk2(a0 - b2f(hi0), a1 - b2f(hi1));
    }
}

// LayerNorm over l, in place, hi/lo layout [j=(g,l)][1024].
// grid = #groups (n*c or n*o2), 256 thr (one v-pair each).
__global__ __launch_bounds__(256) void ln_kernel(
    unsigned int* __restrict__ h_u, const float* __restrict__ lw,
    const float* __restrict__ lb) {
    int nc = blockIdx.x;
    int t = threadIdx.x;
    unsigned int base = nc * 32768 + t;
    float s0 = 0.f, s1 = 0.f, q0 = 0.f, q1 = 0.f;
    for (int l = 0; l < 64; l++) {
        unsigned int hi = h_u[base + l * 512];
        unsigned int lo = h_u[base + l * 512 + 256];
        float f0 = ulo(hi) + ulo(lo), f1 = uhi(hi) + uhi(lo);
        s0 += f0; s1 += f1;
        q0 += f0 * f0; q1 += f1 * f1;
    }
    float m0 = s0 * (1.f / 64.f), m1 = s1 * (1.f / 64.f);
    float v0 = fmaxf(q0 * (1.f / 64.f) - m0 * m0, 0.f);
    float v1 = fmaxf(q1 * (1.f / 64.f) - m1 * m1, 0.f);
    float i0 = 1.f / sqrtf(v0 + 1e-12f);
    float i1 = 1.f / sqrtf(v1 + 1e-12f);
    for (int l = 0; l < 64; l++) {
        unsigned int hi = h_u[base + l * 512];
        unsigned int lo = h_u[base + l * 512 + 256];
        float wl = lw[l], bl = lb[l];
        float f0 = wl * (ulo(hi) + ulo(lo) - m0) * i0 + bl;
        float f1 = wl * (uhi(hi) + uhi(lo) - m1) * i1 + bl;
        unsigned short p0 = f2b(f0), p1 = f2b(f1);
        h_u[base + l * 512] = (unsigned int)p0 | ((unsigned int)p1 << 16);
        h_u[base + l * 512 + 256] = pk2(f0 - b2f(p0), f1 - b2f(p1));
    }
}

// e1[(n,o1,l)][v] = selu(b1[o1] + sum_c W1[o1,c]*h[(n,c,l)][v])
// h hi/lo [j][1024]; e1 single bf16 packed [j2][512] (256 u32/row).
// grid (n,l,vc) = 1024 blocks, 256 thr; weights LDS-transposed [c][o1].
__global__ __launch_bounds__(256) void endmix1(
    const unsigned int* __restrict__ h, const float* __restrict__ w1,
    const float* __restrict__ b1, unsigned int* __restrict__ e1u) {
    __shared__ float wsT[32 * 64];  // [c][o1] 8 KB
    int bid = blockIdx.x;
    int vc = bid & 3, l = (bid >> 2) & 63, n = bid >> 8;
    int t = threadIdx.x;
    int vl = t & 63, q = t >> 6;
    for (int i = t; i < 2048; i += 256) {
        int o1 = i >> 5, c = i & 31;
        wsT[c * 64 + o1] = w1[i];
    }
    __syncthreads();
    float acc[16][2];
#pragma unroll
    for (int oo = 0; oo < 16; oo++) {
        float bb = b1[q * 16 + oo];
        acc[oo][0] = bb;
        acc[oo][1] = bb;
    }
    int uoff = vc * 64 + vl;
    for (int c = 0; c < 32; c++) {
        int j = (n * 32 + c) * 64 + l;
        unsigned int uh = h[j * 512 + uoff], ul = h[j * 512 + 256 + uoff];
        float xl = ulo(uh) + ulo(ul), xh = uhi(uh) + uhi(ul);
#pragma unroll
        for (int ov = 0; ov < 4; ov++) {
            float4 wv = *(const float4*)&wsT[c * 64 + q * 16 + ov * 4];
            acc[ov * 4 + 0][0] += xl * wv.x;
            acc[ov * 4 + 0][1] += xh * wv.x;
            acc[ov * 4 + 1][0] += xl * wv.y;
            acc[ov * 4 + 1][1] += xh * wv.y;
            acc[ov * 4 + 2][0] += xl * wv.z;
            acc[ov * 4 + 2][1] += xh * wv.z;
            acc[ov * 4 + 3][0] += xl * wv.w;
            acc[ov * 4 + 3][1] += xh * wv.w;
        }
    }
#pragma unroll
    for (int oo = 0; oo < 16; oo++) {
        int o1 = q * 16 + oo;
        int j2 = (n * 64 + o1) * 64 + l;
        e1u[j2 * 256 + uoff] = pk2(selu_f(acc[oo][0]), selu_f(acc[oo][1]));
    }
}

// e2[(n,o2,l)][v] = b2[o2] + sum_o1 W2[o2,o1]*e1; e2 stored hi/lo [j2][1024].
// grid (n,l,vc) = 1024 blocks, 256 thr; weights LDS-transposed [o1][o2].
__global__ __launch_bounds__(256) void endmix2(
    const unsigned int* __restrict__ e1u, const float* __restrict__ w2,
    const float* __restrict__ b2, unsigned int* __restrict__ e2u) {
    __shared__ float wsT[64 * 64];  // [o1][o2] 16 KB
    int bid = blockIdx.x;
    int vc = bid & 3, l = (bid >> 2) & 63, n = bid >> 8;
    int t = threadIdx.x;
    int vl = t & 63, q = t >> 6;
    for (int i = t; i < 4096; i += 256) {
        int o2 = i >> 6, o1 = i & 63;
        wsT[o1 * 64 + o2] = w2[i];
    }
    __syncthreads();
    float acc[16][2];
#pragma unroll
    for (int oo = 0; oo < 16; oo++) {
        float bb = b2[q * 16 + oo];
        acc[oo][0] = bb;
        acc[oo][1] = bb;
    }
    int uoff = vc * 64 + vl;
    for (int o1 = 0; o1 < 64; o1++) {
        int j = (n * 64 + o1) * 64 + l;
        unsigned int u = e1u[j * 256 + uoff];
        float xl = ulo(u), xh = uhi(u);
#pragma unroll
        for (int ov = 0; ov < 4; ov++) {
            float4 wv = *(const float4*)&wsT[o1 * 64 + q * 16 + ov * 4];
            acc[ov * 4 + 0][0] += xl * wv.x;
            acc[ov * 4 + 0][1] += xh * wv.x;
            acc[ov * 4 + 1][0] += xl * wv.y;
            acc[ov * 4 + 1][1] += xh * wv.y;
            acc[ov * 4 + 2][0] += xl * wv.z;
            acc[ov * 4 + 2][1] += xh * wv.z;
            acc[ov * 4 + 3][0] += xl * wv.w;
            acc[ov * 4 + 3][1] += xh * wv.w;
        }
    }
#pragma unroll
    for (int oo = 0; oo < 16; oo++) {
        int o2 = q * 16 + oo;
        int j2 = (n * 64 + o2) * 64 + l;
        float a0 = acc[oo][0], a1 = acc[oo][1];
        unsigned short hi0 = f2b(a0), hi1 = f2b(a1);
        e2u[j2 * 512 + uoff] = (unsigned int)hi0 | ((unsigned int)hi1 << 16);
        e2u[j2 * 512 + 256 + uoff] = pk2(a0 - b2f(hi0), a1 - b2f(hi1));
    }
}

// out[n][l][v] = sum_o2 e2[(n,o2,l)][v]. grid 256 = n*64+l, 256 thr (v-pair).
__global__ __launch_bounds__(256) void sum_o2(
    const unsigned int* __restrict__ e2u, float* __restrict__ out) {
    int n = blockIdx.x >> 6, l = blockIdx.x & 63;
    int t = threadIdx.x;
    float s0 = 0.f, s1 = 0.f;
    for (int o2 = 0; o2 < 64; o2++) {
        int j2 = (n * 64 + o2) * 64 + l;
        unsigned int hi = e2u[j2 * 512 + t];
        unsigned int lo = e2u[j2 * 512 + 256 + t];
        s0 += ulo(hi) + ulo(lo);
        s1 += uhi(hi) + uhi(lo);
    }
    float2 r;
    r.x = s0;
    r.y = s1;
    *(float2*)&out[(size_t)(n * 64 + l) * 512 + 2 * t] = r;
}

// ---------------- launch ----------------

extern "C" void kernel_launch(void* const* d_in, const int* in_sizes, int n_in,
                              void* d_out, int out_size, void* d_ws,
                              size_t ws_size, hipStream_t stream) {
    const float* x = (const float*)d_in[0];
    const float* emb1 = (const float*)d_in[1];
    const float* emb2 = (const float*)d_in[2];
    const float* lin1_w = (const float*)d_in[3];
    const float* lin1_b = (const float*)d_in[4];
    const float* lin2_w = (const float*)d_in[5];
    const float* lin2_b = (const float*)d_in[6];
    const float* start_w = (const float*)d_in[7];
    const float* start_b = (const float*)d_in[8];
    const float* g1_w = (const float*)d_in[9];
    const float* g1_b = (const float*)d_in[10];
    const float* g2_w = (const float*)d_in[11];
    const float* g2_b = (const float*)d_in[12];
    const float* ln_w = (const float*)d_in[13];
    const float* ln_b = (const float*)d_in[14];
    const float* end1_w = (const float*)d_in[15];
    const float* end1_b = (const float*)d_in[16];
    const float* end2_w = (const float*)d_in[17];
    const float* end2_b = (const float*)d_in[18];
    float* out = (float*)d_out;

    char* ws = (char*)d_ws;
    float* nv1 = (float*)(ws + 0);
    float* nv2 = (float*)(ws + 131072);
    float* adp = (float*)(ws + 262144);
    unsigned short* a1T = (unsigned short*)(ws + 1310720);
    unsigned short* a2T = (unsigned short*)(ws + 2359296);
    float* rowsump = (float*)(ws + 3407872);
    float* colsum = (float*)(ws + 3409920);
    float* cspart = (float*)(ws + 3412992);
    unsigned short* hA = (unsigned short*)(ws + 4194304);
    unsigned short* hB = (unsigned short*)(ws + 20971520);
    unsigned short* s1 = (unsigned short*)(ws + 37748736);
    unsigned short* s2 = (unsigned short*)(ws + 54525952);  // s2+s3 = 33.5 MB
    unsigned short* s3 = (unsigned short*)(ws + 71303168);
    unsigned short* s4 = (unsigned short*)(ws + 88080384);

    nodevec_kernel<<<512, 64, 0, stream>>>(emb1, lin1_w, lin1_b, nv1);
    nodevec_kernel<<<512, 64, 0, stream>>>(emb2, lin2_w, lin2_b, nv2);
    adjacency_kernel<<<512, 512, 0, stream>>>(nv1, nv2, adp);
    topk_kernel<<<512, 256, 0, stream>>>(adp, rowsump);
    colsum_part<<<16, 256, 0, stream>>>(adp, cspart);
    colsum_red<<<1, 512, 0, stream>>>(cspart, colsum);
    normalize_kernel<<<512, 256, 0, stream>>>(adp, rowsump, colsum, a1T, a2T);

    start_kernel<<<256, 256, 0, stream>>>(x, start_w, start_b, (unsigned int*)hA);

    dim3 pgrid(64, 8);
    unsigned short* cur = hA;
    unsigned short* nxt = hB;
    for (int layer = 0; layer < 2; layer++) {
        const float* w1 = g1_w + layer * 32 * 96;
        const float* bb1 = g1_b + layer * 32;
        const float* w2 = g2_w + layer * 32 * 96;
        const float* bb2 = g2_b + layer * 32;
        prop_pair<true><<<pgrid, 256, 0, stream>>>(cur, cur, cur, a1T, a2T,
                                                   s1, s2);
        prop_pair<false><<<pgrid, 256, 0, stream>>>(s1, s2, cur, a1T, a2T,
                                                    s3, s4);
        chanmix_dual<<<1024, 256, 0, stream>>>(
            (const unsigned int*)cur, (const unsigned int*)s1,
            (const unsigned int*)s3, (const unsigned int*)s2,
            (const unsigned int*)s4, w1, bb1, w2, bb2, (unsigned int*)nxt);
        unsigned short* tmp = cur;
        cur = nxt;
        nxt = tmp;
    }

    // end stage: LN#1 -> end1+selu -> end2 -> LN#2 -> sum over o2
    ln_kernel<<<128, 256, 0, stream>>>((unsigned int*)cur, ln_w, ln_b);
    endmix1<<<1024, 256, 0, stream>>>((const unsigned int*)cur, end1_w, end1_b,
                                      (unsigned int*)s1);
    endmix2<<<1024, 256, 0, stream>>>((const unsigned int*)s1, end2_w, end2_b,
                                      (unsigned int*)s2);
    ln_kernel<<<256, 256, 0, stream>>>((unsigned int*)s2, ln_w, ln_b);
    sum_o2<<<256, 256, 0, stream>>>((const unsigned int*)s2, out);
}